// Round 2
// baseline (45.906 us; speedup 1.0000x reference)
//
#include <hip/hip_runtime.h>
#include <cstdint>
#include <cstddef>

#define BB   32
#define AA   3
#define FF   76
#define NCH  85
#define NL   50
#define NCLS 80
#define CELLS (AA*FF*FF)              /* 17328 */
#define CPB  256
#define BPB  ((CELLS + CPB - 1)/CPB)  /* 68 */

__device__ __forceinline__ float slog(float x) {
    // torch-BCELoss-style clamped log
    return fmaxf(logf(fmaxf(x, 1e-43f)), -100.0f);
}

// ---------------- kernel 1: per-label records + match scatter ----------------
// boxarea: [B][256] floats -- [0..199] = 50 x float4 {l, r, bot, top}; [200..249] = areas
// mrec:    [B][NL][8] floats -- {fx, fy, lw, lh, sc, cls_bits, 0, 0}
// mtab:    [B][CELLS] int, init -1; atomicMax(n) == last-write-wins
// maxn:    [B] int, init 0; max valid label index + 1
__global__ void k_labels(const float* __restrict__ labels,
                         float* __restrict__ boxarea,
                         float* __restrict__ mrec,
                         int*   __restrict__ mtab,
                         int*   __restrict__ maxn) {
    int t = blockIdx.x * blockDim.x + threadIdx.x;
    if (t >= BB * NL) return;
    int b = t / NL, n = t % NL;
    const float* L = labels + (size_t)t * 5;
    float c0 = L[0], x = L[1], y = L[2], w = L[3], h = L[4];
    bool  valid = (c0 + x + y + w + h) > 0.0f;
    float vf = valid ? 1.0f : 0.0f;

    float tx = x * 0.125f, ty = y * 0.125f;
    float tw = w * 0.125f, th = h * 0.125f;
    int   ti = (int)tx, tj = (int)ty;
    float twm = tw * vf, thm = th * vf;

    // ANCHORS / 8 (exact in fp32)
    const float ag[9][2] = {
        {1.5f, 2.0f}, {2.375f, 4.5f}, {5.0f, 3.5f},
        {4.5f, 9.375f}, {9.5f, 6.875f}, {9.0f, 18.25f},
        {17.75f, 13.75f}, {24.0f, 30.375f}, {57.375f, 50.125f}
    };

    float at = twm * thm;
    float best = -1.0f; int bi = 0;
    for (int k = 0; k < 9; ++k) {
        float iw = fminf(twm, ag[k][0]);
        float ih = fminf(thm, ag[k][1]);
        float inter = (iw > 0.0f && ih > 0.0f) ? iw * ih : 0.0f;
        float iou = inter / (at + ag[k][0] * ag[k][1] - inter);
        if (iou > best) { best = iou; bi = k; }   // first-max wins, like jnp.argmax
    }
    int  bn    = bi % 3;
    bool write = (bi < 3) && valid;

    float fx = tx - (float)ti;
    float fy = ty - (float)tj;
    float lw = logf(tw / ag[bn][0] + 1e-16f);
    float lh = logf(th / ag[bn][1] + 1e-16f);
    float sc = sqrtf(2.0f - tw * th * (1.0f / (float)(FF * FF)));
    int   cls = (int)c0;
    float tbx = tx * vf, tby = ty * vf;

    float* BA = boxarea + (size_t)b * 256;
    BA[n * 4 + 0] = tbx - twm * 0.5f;   // left
    BA[n * 4 + 1] = tbx + twm * 0.5f;   // right
    BA[n * 4 + 2] = tby - thm * 0.5f;   // bottom
    BA[n * 4 + 3] = tby + thm * 0.5f;   // top
    BA[200 + n]   = twm * thm;          // area

    float* M = mrec + (size_t)t * 8;
    M[0] = fx; M[1] = fy; M[2] = lw; M[3] = lh;
    M[4] = sc; M[5] = __int_as_float(cls); M[6] = 0.0f; M[7] = 0.0f;

    if (valid) {
        atomicMax(&maxn[b], n + 1);
        if (write) {
            int key = bn * FF * FF + tj * FF + ti;
            atomicMax(&mtab[(size_t)b * CELLS + key], n);  // last write (max n) wins
        }
    }
}

// ---------------- kernel 2: per-cell loss ----------------
__global__ void __launch_bounds__(CPB) k_main(const float* __restrict__ outp,
                                              const float* __restrict__ pred,
                                              const float* __restrict__ boxarea,
                                              const float* __restrict__ mrec,
                                              const int*   __restrict__ mtab,
                                              const int*   __restrict__ maxn_a,
                                              float* __restrict__ partial) {
    __shared__ float S[256];     // staged boxarea for this batch
    __shared__ float red[CPB];

    int bid = blockIdx.x;
    int b   = bid / BPB;
    int blk = bid % BPB;

    if (threadIdx.x < 64) {
        ((float4*)S)[threadIdx.x] = ((const float4*)(boxarea + (size_t)b * 256))[threadIdx.x];
    }
    __syncthreads();

    int   cell = blk * CPB + (int)threadIdx.x;
    float loss = 0.0f;

    if (cell < CELLS) {
        size_t ci = (size_t)b * CELLS + cell;
        float4 pb = ((const float4*)pred)[ci];          // coalesced 16B
        int    mn = mtab[ci];                           // coalesced 4B
        float  p4 = outp[ci * NCH + 4];                 // strided gather
        int    mx = maxn_a[b];                          // uniform

        float plx = pb.x - pb.z * 0.5f, prx = pb.x + pb.z * 0.5f;
        float ply = pb.y - pb.w * 0.5f, pry = pb.y + pb.w * 0.5f;
        float ap  = pb.z * pb.w;

        float bestiou = 0.0f;
        #pragma unroll 4
        for (int n = 0; n < mx; ++n) {
            float4 tb   = ((const float4*)S)[n];        // ds_read_b128, broadcast
            float  area = S[200 + n];                   // ds_read_b32, broadcast
            float lx = fmaxf(plx, tb.x);
            float rx = fminf(prx, tb.y);
            float ly = fmaxf(ply, tb.z);
            float ry = fminf(pry, tb.w);
            float w = rx - lx, h = ry - ly;
            float inter = (fminf(w, h) > 0.0f) ? w * h : 0.0f;
            float iou = inter * __builtin_amdgcn_rcpf(ap + area - inter);
            bestiou = fmaxf(bestiou, iou);
        }

        if (mn >= 0) {
            const float* r  = mrec + ((size_t)b * NL + mn) * 8;
            const float* op = outp + ci * NCH;
            loss += -slog(p4);                          // obj, t=1
            float s = r[4], s2 = s * s;
            float t0 = r[0], t1 = r[1];
            float p0 = op[0], p1 = op[1];
            loss += -s2 * (t0 * slog(p0) + (1.0f - t0) * slog(1.0f - p0));
            loss += -s2 * (t1 * slog(p1) + (1.0f - t1) * slog(1.0f - p1));
            float d0 = (op[2] - r[2]) * s;
            float d1 = (op[3] - r[3]) * s;
            loss += 0.5f * (d0 * d0 + d1 * d1);
            int cls = __float_as_int(r[5]);
            #pragma unroll 4
            for (int c = 0; c < NCLS; ++c) {
                float p = op[5 + c];
                loss += (c == cls) ? -slog(p) : -slog(1.0f - p);
            }
        } else if (!(bestiou > 0.7f)) {
            loss += -slog(1.0f - p4);                   // obj, t=0, not ignored
        }
    }

    red[threadIdx.x] = loss;
    __syncthreads();
    for (int s = CPB / 2; s > 0; s >>= 1) {
        if ((int)threadIdx.x < s) red[threadIdx.x] += red[threadIdx.x + s];
        __syncthreads();
    }
    if (threadIdx.x == 0) partial[bid] = red[0];
}

// ---------------- kernel 3: deterministic final reduce ----------------
__global__ void k_reduce(const float* __restrict__ partial, float* __restrict__ out, int n) {
    __shared__ float red[256];
    float s = 0.0f;
    for (int i = threadIdx.x; i < n; i += 256) s += partial[i];
    red[threadIdx.x] = s;
    __syncthreads();
    for (int k = 128; k > 0; k >>= 1) {
        if ((int)threadIdx.x < k) red[threadIdx.x] += red[threadIdx.x + k];
        __syncthreads();
    }
    if (threadIdx.x == 0) out[0] = red[0];
}

extern "C" void kernel_launch(void* const* d_in, const int* in_sizes, int n_in,
                              void* d_out, int out_size, void* d_ws, size_t ws_size,
                              hipStream_t stream) {
    const float* outp   = (const float*)d_in[0];  // [32,3,76,76,85] probabilities
    const float* pred   = (const float*)d_in[1];  // [32,3,76,76,4] decoded boxes
    const float* labels = (const float*)d_in[2];  // [32,50,5]

    // ws layout (float elements)
    float* boxarea = (float*)d_ws;                          // 32*256      = 8192
    float* mrec    = boxarea + (size_t)BB * 256;            // 32*50*8     = 12800
    float* partial = mrec + (size_t)BB * NL * 8;            // 32*68       = 2176
    int*   mtab    = (int*)(partial + BB * BPB);            // 32*17328    = 554496
    int*   maxn    = mtab + (size_t)BB * CELLS;             // 32

    hipMemsetAsync(mtab, 0xFF, (size_t)BB * CELLS * sizeof(int), stream);  // -1
    hipMemsetAsync(maxn, 0x00, (size_t)BB * sizeof(int), stream);

    k_labels<<<(BB * NL + 255) / 256, 256, 0, stream>>>(labels, boxarea, mrec, mtab, maxn);
    k_main<<<BB * BPB, CPB, 0, stream>>>(outp, pred, boxarea, mrec, mtab, maxn, partial);
    k_reduce<<<1, 256, 0, stream>>>(partial, (float*)d_out, BB * BPB);
}

// Round 3
// 32.906 us; speedup vs baseline: 1.3951x; 1.3951x over previous
//
#include <hip/hip_runtime.h>
#include <cstdint>
#include <cstddef>

#define BB   32
#define AA   3
#define FF   76
#define NCH  85
#define NL   50
#define NCLS 80
#define CELLS (AA*FF*FF)              /* 17328 */
#define CPB  256
#define BPB  ((CELLS + CPB - 1)/CPB)  /* 68 */
#define NPART (BB*BPB)                /* 2176 */

__device__ __forceinline__ float slog(float x) {
    // torch-BCELoss-style clamped log
    return fmaxf(logf(fmaxf(x, 1e-43f)), -100.0f);
}

// ---------------- fused kernel: records in-block + per-cell loss ----------------
__global__ void __launch_bounds__(CPB) k_main(const float* __restrict__ outp,
                                              const float* __restrict__ pred,
                                              const float* __restrict__ labels,
                                              float* __restrict__ partial) {
    __shared__ float4 Sbox[NL];        // truth {l, r, bot, top}
    __shared__ float2 Sak[NL];         // {area, key_bits}
    __shared__ float  Srec[NL][6];     // {fx, fy, lw, lh, sc, cls_bits}
    __shared__ int    Smx;
    __shared__ float  red[CPB];

    int bid = blockIdx.x;
    int b   = bid / BPB;
    int blk = bid % BPB;

    int    cell = blk * CPB + (int)threadIdx.x;
    bool   live = cell < CELLS;
    size_t ci   = (size_t)b * CELLS + (size_t)(live ? cell : 0);

    // issue the big-latency loads early; consumed after the record phase
    float4 pb = ((const float4*)pred)[ci];
    float  p4 = outp[ci * NCH + 4];

    // ---- wave 0: build this batch's label records in LDS ----
    if (threadIdx.x < 64) {
        int  n   = (int)threadIdx.x;
        bool has = n < NL;
        bool valid = false;
        if (has) {
            const float* L = labels + ((size_t)b * NL + n) * 5;
            float c0 = L[0], x = L[1], y = L[2], w = L[3], h = L[4];
            valid = (c0 + x + y + w + h) > 0.0f;
            float vf = valid ? 1.0f : 0.0f;

            float tx = x * 0.125f, ty = y * 0.125f;
            float tw = w * 0.125f, th = h * 0.125f;
            int   ti = (int)tx, tj = (int)ty;
            float twm = tw * vf, thm = th * vf;

            const float ag[9][2] = {   // ANCHORS / 8, exact in fp32
                {1.5f, 2.0f}, {2.375f, 4.5f}, {5.0f, 3.5f},
                {4.5f, 9.375f}, {9.5f, 6.875f}, {9.0f, 18.25f},
                {17.75f, 13.75f}, {24.0f, 30.375f}, {57.375f, 50.125f}
            };
            float at = twm * thm;
            float best = -1.0f; int bi = 0;
            #pragma unroll
            for (int k = 0; k < 9; ++k) {
                float iw = fminf(twm, ag[k][0]);
                float ih = fminf(thm, ag[k][1]);
                float inter = (iw > 0.0f && ih > 0.0f) ? iw * ih : 0.0f;
                float iou = inter / (at + ag[k][0] * ag[k][1] - inter);
                if (iou > best) { best = iou; bi = k; }   // first-max wins (jnp.argmax)
            }
            int  bn    = bi % 3;
            bool write = (bi < 3) && valid;
            int  key   = write ? (bn * FF * FF + tj * FF + ti) : -1;

            float tbx = tx * vf, tby = ty * vf;
            Sbox[n] = make_float4(tbx - twm * 0.5f, tbx + twm * 0.5f,
                                  tby - thm * 0.5f, tby + thm * 0.5f);
            Sak[n]  = make_float2(twm * thm, __int_as_float(key));
            Srec[n][0] = tx - (float)ti;
            Srec[n][1] = ty - (float)tj;
            Srec[n][2] = logf(tw / ag[bn][0] + 1e-16f);
            Srec[n][3] = logf(th / ag[bn][1] + 1e-16f);
            Srec[n][4] = sqrtf(2.0f - tw * th * (1.0f / (float)(FF * FF)));
            Srec[n][5] = __int_as_float((int)c0);
        }
        unsigned long long mb = __ballot(has && valid);
        if (threadIdx.x == 0) Smx = mb ? (64 - __builtin_clzll(mb)) : 0;
    }
    __syncthreads();

    float loss = 0.0f;
    if (live) {
        float plx = pb.x - pb.z * 0.5f, prx = pb.x + pb.z * 0.5f;
        float ply = pb.y - pb.w * 0.5f, pry = pb.y + pb.w * 0.5f;
        float ap  = pb.z * pb.w;

        int   mx = Smx;
        float bestiou = 0.0f;
        int   mn = -1;
        #pragma unroll 4
        for (int n = 0; n < mx; ++n) {
            float4 tb = Sbox[n];                        // ds_read_b128, broadcast
            float2 ak = Sak[n];                         // ds_read_b64,  broadcast
            float lx = fmaxf(plx, tb.x);
            float rx = fminf(prx, tb.y);
            float ly = fmaxf(ply, tb.z);
            float ry = fminf(pry, tb.w);
            float w = rx - lx, h = ry - ly;
            float inter = (fminf(w, h) > 0.0f) ? w * h : 0.0f;
            bestiou = fmaxf(bestiou, inter * __builtin_amdgcn_rcpf(ap + ak.x - inter));
            if (__float_as_int(ak.y) == cell) mn = n;   // last write wins
        }

        if (mn >= 0) {
            const float* op = outp + ci * NCH;
            const float* r  = Srec[mn];
            loss += -slog(p4);                          // obj, t=1
            float s = r[4], s2 = s * s;
            float t0 = r[0], t1 = r[1];
            float p0 = op[0], p1 = op[1];
            loss += -s2 * (t0 * slog(p0) + (1.0f - t0) * slog(1.0f - p0));
            loss += -s2 * (t1 * slog(p1) + (1.0f - t1) * slog(1.0f - p1));
            float d0 = (op[2] - r[2]) * s;
            float d1 = (op[3] - r[3]) * s;
            loss += 0.5f * (d0 * d0 + d1 * d1);
            // class BCE, branch-free: sum -slog(1-p) over all, fix up true class
            int   cls = __float_as_int(r[5]);
            float cl  = 0.0f;
            #pragma unroll 8
            for (int c = 0; c < NCLS; ++c) cl += slog(1.0f - op[5 + c]);
            float pc = op[5 + cls];
            loss += -cl + slog(1.0f - pc) - slog(pc);
        } else if (!(bestiou > 0.7f)) {
            loss += -slog(1.0f - p4);                   // obj, t=0, not ignored
        }
    }

    red[threadIdx.x] = loss;
    __syncthreads();
    for (int s = CPB / 2; s > 0; s >>= 1) {
        if ((int)threadIdx.x < s) red[threadIdx.x] += red[threadIdx.x + s];
        __syncthreads();
    }
    if (threadIdx.x == 0) partial[bid] = red[0];
}

// ---------------- deterministic final reduce ----------------
__global__ void k_reduce(const float* __restrict__ partial, float* __restrict__ out) {
    __shared__ float red[256];
    float s = 0.0f;
    for (int i = threadIdx.x; i < NPART; i += 256) s += partial[i];
    red[threadIdx.x] = s;
    __syncthreads();
    for (int k = 128; k > 0; k >>= 1) {
        if ((int)threadIdx.x < k) red[threadIdx.x] += red[threadIdx.x + k];
        __syncthreads();
    }
    if (threadIdx.x == 0) out[0] = red[0];
}

extern "C" void kernel_launch(void* const* d_in, const int* in_sizes, int n_in,
                              void* d_out, int out_size, void* d_ws, size_t ws_size,
                              hipStream_t stream) {
    const float* outp   = (const float*)d_in[0];  // [32,3,76,76,85] probabilities
    const float* pred   = (const float*)d_in[1];  // [32,3,76,76,4] decoded boxes
    const float* labels = (const float*)d_in[2];  // [32,50,5]

    float* partial = (float*)d_ws;                // 2176 floats, fully overwritten each call

    k_main<<<NPART, CPB, 0, stream>>>(outp, pred, labels, partial);
    k_reduce<<<1, 256, 0, stream>>>(partial, (float*)d_out);
}